// Round 1
// baseline (9374.701 us; speedup 1.0000x reference)
//
#include <hip/hip_runtime.h>
#include <hip/hip_bf16.h>
#include <cstdint>

#define NT   900
#define EMB  1152
#define NH   16
#define DHD  72
#define DHH  36
#define NL   6
#define FFD  4608
#define MHD  4608
#define OUTD 2048
#define NM   225

// ---------------- patch extraction: pixels -> [900, 1536] ----------------
__global__ __launch_bounds__(256) void k_patch(const float* __restrict__ pix,
                                               float* __restrict__ xp) {
    int idx = blockIdx.x * 256 + threadIdx.x;
    if (idx >= NT * 1536) return;
    int t = idx / 1536, f = idx - t * 1536;
    // t = ((ii*15 + jj)*2 + mh)*2 + mw
    int mw = t & 1, mh = (t >> 1) & 1;
    int tq = t >> 2;
    int jj = tq % 15, ii = tq / 15;
    // f = c*512 + tp*256 + ph*16 + pw   (tp duplicates, value identical)
    int pw = f & 15, ph = (f >> 4) & 15, c = f >> 9;
    int Hi = (ii * 2 + mh) * 16 + ph;
    int Wi = (jj * 2 + mw) * 16 + pw;
    float p = pix[((size_t)c * 480 + Hi) * 480 + Wi];
    xp[idx] = (p - 127.5f) * (1.0f / 127.5f);
}

// ---------------- layernorm over C cols, one block per row ----------------
__global__ __launch_bounds__(256) void k_ln(const float* __restrict__ x,
                                            const float* __restrict__ w,
                                            const float* __restrict__ b,
                                            float* __restrict__ y, int C) {
    int row = blockIdx.x;
    int tid = threadIdx.x;
    const float* xr = x + (size_t)row * C;
    float s = 0.f, ss = 0.f;
    for (int c = tid; c < C; c += 256) { float v = xr[c]; s += v; ss += v * v; }
    for (int off = 32; off; off >>= 1) {
        s  += __shfl_down(s,  off, 64);
        ss += __shfl_down(ss, off, 64);
    }
    __shared__ float rs[4], rss[4];
    int wid = tid >> 6, lane = tid & 63;
    if (lane == 0) { rs[wid] = s; rss[wid] = ss; }
    __syncthreads();
    float S  = rs[0] + rs[1] + rs[2] + rs[3];
    float SS = rss[0] + rss[1] + rss[2] + rss[3];
    float mu  = S / C;
    float var = SS / C - mu * mu;
    float inv = rsqrtf(var + 1e-6f);
    float* yr = y + (size_t)row * C;
    for (int c = tid; c < C; c += 256) yr[c] = (xr[c] - mu) * inv * w[c] + b[c];
}

// ---------------- generic f32 GEMM: C[M,N] = act(A[M,K] @ W[N,K]^T + bias) + res
__device__ __forceinline__ float gelu_f(float x) {
    return 0.5f * x * (1.0f + tanhf(0.7978845608f * (x + 0.044715f * x * x * x)));
}

template <int ACT>
__global__ __launch_bounds__(256) void k_gemm(const float* __restrict__ A,
                                              const float* __restrict__ W,
                                              const float* __restrict__ bias,
                                              const float* __restrict__ res,
                                              float* __restrict__ C,
                                              int M, int N, int K) {
    __shared__ float As[32][64];
    __shared__ float Ws[32][64];
    int tid = threadIdx.x;
    int tx = tid & 15, ty = tid >> 4;
    int row0 = blockIdx.y * 64, col0 = blockIdx.x * 64;
    float acc[4][4] = {};
    for (int k0 = 0; k0 < K; k0 += 32) {
#pragma unroll
        for (int i = 0; i < 2; i++) {
            int idx = tid + i * 256;          // 0..511 (float4 index)
            int m  = idx >> 3;                // 0..63
            int kk = (idx & 7) << 2;          // 0,4,...,28
            int gr = row0 + m; if (gr > M - 1) gr = M - 1;   // clamp (writes guarded)
            const float4 va = *(const float4*)(A + (size_t)gr * K + k0 + kk);
            As[kk][m] = va.x; As[kk + 1][m] = va.y; As[kk + 2][m] = va.z; As[kk + 3][m] = va.w;
            int gc = col0 + m;                // N is always a multiple of 64
            const float4 vb = *(const float4*)(W + (size_t)gc * K + k0 + kk);
            Ws[kk][m] = vb.x; Ws[kk + 1][m] = vb.y; Ws[kk + 2][m] = vb.z; Ws[kk + 3][m] = vb.w;
        }
        __syncthreads();
#pragma unroll
        for (int kk = 0; kk < 32; kk++) {
            const float4 a = *(const float4*)&As[kk][ty << 2];
            const float4 b = *(const float4*)&Ws[kk][tx << 2];
            float av[4] = { a.x, a.y, a.z, a.w };
            float bv[4] = { b.x, b.y, b.z, b.w };
#pragma unroll
            for (int i = 0; i < 4; i++)
#pragma unroll
                for (int j = 0; j < 4; j++) acc[i][j] += av[i] * bv[j];
        }
        __syncthreads();
    }
#pragma unroll
    for (int i = 0; i < 4; i++) {
        int r = row0 + (ty << 2) + i;
        if (r < M) {
#pragma unroll
            for (int j = 0; j < 4; j++) {
                int c = col0 + (tx << 2) + j;
                float v = acc[i][j] + bias[c];
                if (res) v += res[(size_t)r * N + c];
                if (ACT == 1) v = gelu_f(v);
                C[(size_t)r * N + c] = v;
            }
        }
    }
}

// ---------------- qkv [900,3456] -> rope(q),rope(k),v as [16,900,72] ----------------
__global__ __launch_bounds__(256) void k_rope(const float* __restrict__ qkv,
                                              const float* __restrict__ cs,
                                              const float* __restrict__ sn,
                                              float* __restrict__ q,
                                              float* __restrict__ k,
                                              float* __restrict__ v) {
    int idx = blockIdx.x * 256 + threadIdx.x;
    if (idx >= NT * EMB) return;
    int t = idx / EMB, e = idx - t * EMB;
    int h = e / DHD, d = e - h * DHD;
    const float* base = qkv + (size_t)t * 3 * EMB;
    float c = cs[t * DHD + d], s = sn[t * DHD + d];
    int   d2 = (d < DHH) ? d + DHH : d - DHH;
    float sg = (d < DHH) ? -1.f : 1.f;
    float qv = base[e],            kv = base[EMB + e];
    float qr = base[h * DHD + d2], kr = base[EMB + h * DHD + d2];
    size_t oi = ((size_t)h * NT + t) * DHD + d;
    q[oi] = qv * c + sg * qr * s;
    k[oi] = kv * c + sg * kr * s;
    v[oi] = base[2 * EMB + e];
}

// ---------------- attention: one block per (16-query tile, head) ----------------
__global__ __launch_bounds__(256) void k_attn(const float* __restrict__ q,
                                              const float* __restrict__ k,
                                              const float* __restrict__ v,
                                              float* __restrict__ o) {
    __shared__ float sc[16][NT];     // 57.6 KB
    __shared__ float qs[16][DHD];    //  4.6 KB
    int h  = blockIdx.y;
    int q0 = blockIdx.x * 16;
    int tid = threadIdx.x;
    for (int i = tid; i < 16 * DHD; i += 256) {
        int qi = i / DHD, d = i - qi * DHD;
        int t = q0 + qi;
        qs[qi][d] = (t < NT) ? q[((size_t)h * NT + t) * DHD + d] : 0.f;
    }
    __syncthreads();
    int qi = tid >> 4;      // 0..15 (all 16 lanes of a row are in one wave)
    int l16 = tid & 15;
    const float* kh = k + (size_t)h * NT * DHD;
    for (int kt = l16; kt < NT; kt += 16) {
        float acc = 0.f;
        const float* kr = kh + (size_t)kt * DHD;
#pragma unroll 8
        for (int d = 0; d < DHD; d++) acc += qs[qi][d] * kr[d];
        sc[qi][kt] = acc;
    }
    __syncthreads();
    // row softmax (16 lanes per row, same wave)
    float mx = -1e30f;
    for (int kt = l16; kt < NT; kt += 16) mx = fmaxf(mx, sc[qi][kt]);
    for (int off = 8; off; off >>= 1) mx = fmaxf(mx, __shfl_xor(mx, off, 16));
    float sum = 0.f;
    for (int kt = l16; kt < NT; kt += 16) {
        float e = __expf(sc[qi][kt] - mx);
        sc[qi][kt] = e;
        sum += e;
    }
    for (int off = 8; off; off >>= 1) sum += __shfl_xor(sum, off, 16);
    float inv = 1.f / sum;
    __syncthreads();
    // PV
    const float* vh = v + (size_t)h * NT * DHD;
    int t = q0 + qi;
    if (t < NT) {
        for (int d = l16; d < DHD; d += 16) {
            float acc = 0.f;
            for (int kt = 0; kt < NT; kt++) acc += sc[qi][kt] * vh[(size_t)kt * DHD + d];
            o[(size_t)t * EMB + h * DHD + d] = acc * inv;
        }
    }
}

extern "C" void kernel_launch(void* const* d_in, const int* in_sizes, int n_in,
                              void* d_out, int out_size, void* d_ws, size_t ws_size,
                              hipStream_t stream) {
    const float* pix     = (const float*)d_in[0];
    const float* patch_w = (const float*)d_in[1];
    const float* patch_b = (const float*)d_in[2];
    const float* pos_emb = (const float*)d_in[3];
    const float* cosb    = (const float*)d_in[4];
    const float* sinb    = (const float*)d_in[5];
    const float* ln1_w   = (const float*)d_in[6];
    const float* ln1_b   = (const float*)d_in[7];
    const float* qkv_w   = (const float*)d_in[8];
    const float* qkv_b   = (const float*)d_in[9];
    const float* proj_w  = (const float*)d_in[10];
    const float* proj_b  = (const float*)d_in[11];
    const float* ln2_w   = (const float*)d_in[12];
    const float* ln2_b   = (const float*)d_in[13];
    const float* fc1_w   = (const float*)d_in[14];
    const float* fc1_b   = (const float*)d_in[15];
    const float* fc2_w   = (const float*)d_in[16];
    const float* fc2_b   = (const float*)d_in[17];
    const float* dsn_w   = (const float*)d_in[18];
    const float* dsn_b   = (const float*)d_in[19];
    const float* ds1_w   = (const float*)d_in[20];
    const float* ds1_b   = (const float*)d_in[21];
    const float* ds2_w   = (const float*)d_in[22];
    const float* ds2_b   = (const float*)d_in[23];
    const float* mn_w    = (const float*)d_in[24];
    const float* mn_b    = (const float*)d_in[25];
    const float* mf1_w   = (const float*)d_in[26];
    const float* mf1_b   = (const float*)d_in[27];
    const float* mf2_w   = (const float*)d_in[28];
    const float* mf2_b   = (const float*)d_in[29];
    float* out = (float*)d_out;

    float* ws = (float*)d_ws;
    size_t off = 0;
    auto alloc = [&](size_t n) { float* p = ws + off; off += n; return p; };
    float* h   = alloc((size_t)NT * EMB);
    float* hn  = alloc((size_t)NT * EMB);
    float* qkv = alloc((size_t)NT * 3 * EMB);
    float* qb  = alloc((size_t)NH * NT * DHD);
    float* kb  = alloc((size_t)NH * NT * DHD);
    float* vb  = alloc((size_t)NH * NT * DHD);
    float* ob  = alloc((size_t)NT * EMB);
    float* t1  = alloc((size_t)NT * FFD);
    float* t2  = alloc((size_t)NM * MHD);
    float* xp  = t1;   // patch matrix [900,1536] reuses t1 (free at that point)

    const int MB = (NT + 63) / 64;   // 15 row tiles for 900 tokens
    const int MBm = (NM + 63) / 64;  // 4 row tiles for 225 merged tokens

    k_patch<<<dim3((NT * 1536 + 255) / 256), 256, 0, stream>>>(pix, xp);
    k_gemm<0><<<dim3(EMB / 64, MB), 256, 0, stream>>>(xp, patch_w, patch_b, pos_emb, h,
                                                      NT, EMB, 1536);
    for (int l = 0; l < NL; ++l) {
        k_ln<<<NT, 256, 0, stream>>>(h, ln1_w + l * EMB, ln1_b + l * EMB, hn, EMB);
        k_gemm<0><<<dim3(3 * EMB / 64, MB), 256, 0, stream>>>(
            hn, qkv_w + (size_t)l * 3 * EMB * EMB, qkv_b + l * 3 * EMB, nullptr, qkv,
            NT, 3 * EMB, EMB);
        k_rope<<<dim3((NT * EMB + 255) / 256), 256, 0, stream>>>(qkv, cosb, sinb, qb, kb, vb);
        k_attn<<<dim3((NT + 15) / 16, NH), 256, 0, stream>>>(qb, kb, vb, ob);
        k_gemm<0><<<dim3(EMB / 64, MB), 256, 0, stream>>>(
            ob, proj_w + (size_t)l * EMB * EMB, proj_b + l * EMB, h, h, NT, EMB, EMB);
        k_ln<<<NT, 256, 0, stream>>>(h, ln2_w + l * EMB, ln2_b + l * EMB, hn, EMB);
        k_gemm<1><<<dim3(FFD / 64, MB), 256, 0, stream>>>(
            hn, fc1_w + (size_t)l * FFD * EMB, fc1_b + l * FFD, nullptr, t1, NT, FFD, EMB);
        k_gemm<0><<<dim3(EMB / 64, MB), 256, 0, stream>>>(
            t1, fc2_w + (size_t)l * EMB * FFD, fc2_b + l * EMB, h, h, NT, EMB, FFD);
        if (l == 2 || l == 5) {
            int d = (l == 2) ? 0 : 1;
            k_ln<<<NM, 256, 0, stream>>>(h, dsn_w + d * MHD, dsn_b + d * MHD, t1, MHD);
            k_gemm<1><<<dim3(MHD / 64, MBm), 256, 0, stream>>>(
                t1, ds1_w + (size_t)d * MHD * MHD, ds1_b + d * MHD, nullptr, t2,
                NM, MHD, MHD);
            k_gemm<0><<<dim3(OUTD / 64, MBm), 256, 0, stream>>>(
                t2, ds2_w + (size_t)d * OUTD * MHD, ds2_b + d * OUTD, nullptr,
                out + (size_t)d * NM * OUTD, NM, OUTD, MHD);
        }
    }
    k_ln<<<NT, 256, 0, stream>>>(h, mn_w, mn_b, hn, EMB);
    k_gemm<1><<<dim3(MHD / 64, MBm), 256, 0, stream>>>(hn, mf1_w, mf1_b, nullptr, t1,
                                                       NM, MHD, MHD);
    k_gemm<0><<<dim3(OUTD / 64, MBm), 256, 0, stream>>>(t1, mf2_w, mf2_b, nullptr,
                                                        out + (size_t)2 * NM * OUTD,
                                                        NM, OUTD, MHD);
}

// Round 3
// 2691.448 us; speedup vs baseline: 3.4831x; 3.4831x over previous
//
#include <hip/hip_runtime.h>
#include <hip/hip_bf16.h>
#include <cstdint>

#define NT   900
#define EMB  1152
#define NH   16
#define DHD  72
#define DHH  36
#define DHP  96      // padded head dim (3*32)
#define KVP  928     // padded kv length (29*32)
#define NL   6
#define FFD  4608
#define MHD  4608
#define OUTD 2048
#define NM   225

typedef __attribute__((ext_vector_type(8))) short short8;
typedef __attribute__((ext_vector_type(4))) float f32x4;

__device__ __forceinline__ ushort f2bf(float f) {
    uint32_t u = __float_as_uint(f);
    uint32_t r = u + 0x7FFF + ((u >> 16) & 1);
    return (ushort)(r >> 16);
}
__device__ __forceinline__ float bf2f(ushort u) {
    return __uint_as_float(((uint32_t)u) << 16);
}
__device__ __forceinline__ float gelu_f(float x) {
    return 0.5f * x * (1.0f + tanhf(0.7978845608f * (x + 0.044715f * x * x * x)));
}

// ---------------- patch extraction: pixels -> bf16 [900, 1536] ----------------
__global__ __launch_bounds__(256) void k_patch(const float* __restrict__ pix,
                                               ushort* __restrict__ xp) {
    int idx = blockIdx.x * 256 + threadIdx.x;
    if (idx >= NT * 1536) return;
    int t = idx / 1536, f = idx - t * 1536;
    int mw = t & 1, mh = (t >> 1) & 1;
    int tq = t >> 2;
    int jj = tq % 15, ii = tq / 15;
    int pw = f & 15, ph = (f >> 4) & 15, c = f >> 9;
    int Hi = (ii * 2 + mh) * 16 + ph;
    int Wi = (jj * 2 + mw) * 16 + pw;
    float p = pix[((size_t)c * 480 + Hi) * 480 + Wi];
    xp[idx] = f2bf((p - 127.5f) * (1.0f / 127.5f));
}

// ---------------- layernorm f32 in -> bf16 out, one block per row ----------------
__global__ __launch_bounds__(256) void k_ln(const float* __restrict__ x,
                                            const float* __restrict__ w,
                                            const float* __restrict__ b,
                                            ushort* __restrict__ y, int C) {
    int row = blockIdx.x;
    int tid = threadIdx.x;
    const float* xr = x + (size_t)row * C;
    float s = 0.f, ss = 0.f;
    for (int c = tid; c < C; c += 256) { float v = xr[c]; s += v; ss += v * v; }
    for (int off = 32; off; off >>= 1) {
        s  += __shfl_down(s,  off, 64);
        ss += __shfl_down(ss, off, 64);
    }
    __shared__ float rs[4], rss[4];
    int wid = tid >> 6, lane = tid & 63;
    if (lane == 0) { rs[wid] = s; rss[wid] = ss; }
    __syncthreads();
    float S  = rs[0] + rs[1] + rs[2] + rs[3];
    float SS = rss[0] + rss[1] + rss[2] + rss[3];
    float mu  = S / C;
    float var = SS / C - mu * mu;
    float inv = rsqrtf(var + 1e-6f);
    ushort* yr = y + (size_t)row * C;
    for (int c = tid; c < C; c += 256) yr[c] = f2bf((xr[c] - mu) * inv * w[c] + b[c]);
}

// ---------------- bf16 MFMA GEMM ----------------
// C[M,Nw] = act(A[M,K](bf16) @ W[N,K]^T + bias) + res
// W is f32 (WBF16=0, converted during staging) or bf16 (WBF16=1).
// Output f32 (OBF16=0) or bf16 (OBF16=1). ldc = C/res row stride.
// blockIdx.z batches (strides in elements).
template <int ACT, int WBF16, int OBF16>
__global__ __launch_bounds__(256) void k_mm(const ushort* __restrict__ A,
                                            const void* __restrict__ Wp,
                                            const float* __restrict__ bias,
                                            const float* __restrict__ res,
                                            void* __restrict__ Cp,
                                            int M, int N, int K, int ldc, int Nw,
                                            long as_, long ws_, long cs_) {
    __shared__ __align__(16) ushort As[64 * 40];
    __shared__ __align__(16) ushort Bs[64 * 40];
    int z = blockIdx.z;
    A += (size_t)z * as_;
    const float*  Wf = (const float*)Wp + (size_t)z * ws_;
    const ushort* Wb = (const ushort*)Wp + (size_t)z * ws_;
    float*  Cf = (float*)Cp + (size_t)z * cs_;
    ushort* Cb = (ushort*)Cp + (size_t)z * cs_;

    int tid = threadIdx.x;
    int row0 = blockIdx.y * 64, col0 = blockIdx.x * 64;

    int sm = tid >> 2, sp = tid & 3;
    int ar = row0 + sm; if (ar > M - 1) ar = M - 1;
    int wr = col0 + sm; if (wr > N - 1) wr = N - 1;
    const ushort* aptr = A + (size_t)ar * K;

    int lane = tid & 63, wid = tid >> 6;
    int wrr = (wid >> 1) * 32, wcc = (wid & 1) * 32;
    int fr = lane & 15, kg = lane >> 4;

    f32x4 acc[2][2] = {};

    for (int k0 = 0; k0 < K; k0 += 32) {
        // stage A (bf16 source): 16B per thread
        *(uint4*)&As[sm * 40 + sp * 8] = *(const uint4*)(aptr + k0 + sp * 8);
        // stage W
        if (WBF16) {
            *(uint4*)&Bs[sm * 40 + sp * 8] =
                *(const uint4*)(Wb + (size_t)wr * K + k0 + sp * 8);
        } else {
            const float4 w0 = *(const float4*)(Wf + (size_t)wr * K + k0 + sp * 8);
            const float4 w1 = *(const float4*)(Wf + (size_t)wr * K + k0 + sp * 8 + 4);
            ushort tmp[8] = { f2bf(w0.x), f2bf(w0.y), f2bf(w0.z), f2bf(w0.w),
                              f2bf(w1.x), f2bf(w1.y), f2bf(w1.z), f2bf(w1.w) };
            *(uint4*)&Bs[sm * 40 + sp * 8] = *(const uint4*)tmp;
        }
        __syncthreads();
        short8 a0 = *(const short8*)&As[(wrr + fr) * 40 + kg * 8];
        short8 a1 = *(const short8*)&As[(wrr + 16 + fr) * 40 + kg * 8];
        short8 b0 = *(const short8*)&Bs[(wcc + fr) * 40 + kg * 8];
        short8 b1 = *(const short8*)&Bs[(wcc + 16 + fr) * 40 + kg * 8];
        acc[0][0] = __builtin_amdgcn_mfma_f32_16x16x32_bf16(a0, b0, acc[0][0], 0, 0, 0);
        acc[0][1] = __builtin_amdgcn_mfma_f32_16x16x32_bf16(a0, b1, acc[0][1], 0, 0, 0);
        acc[1][0] = __builtin_amdgcn_mfma_f32_16x16x32_bf16(a1, b0, acc[1][0], 0, 0, 0);
        acc[1][1] = __builtin_amdgcn_mfma_f32_16x16x32_bf16(a1, b1, acc[1][1], 0, 0, 0);
        __syncthreads();
    }

#pragma unroll
    for (int fi = 0; fi < 2; fi++)
#pragma unroll
        for (int fj = 0; fj < 2; fj++)
#pragma unroll
            for (int r = 0; r < 4; r++) {
                int row = row0 + wrr + fi * 16 + (lane >> 4) * 4 + r;
                int col = col0 + wcc + fj * 16 + (lane & 15);
                if (row < M && col < Nw) {
                    float v = acc[fi][fj][r];
                    if (bias) v += bias[col];
                    if (res)  v += res[(size_t)row * ldc + col];
                    if (ACT == 1) v = gelu_f(v);
                    if (OBF16) Cb[(size_t)row * ldc + col] = f2bf(v);
                    else       Cf[(size_t)row * ldc + col] = v;
                }
            }
}

// ---------------- qkv f32 [900,3456] -> rope(q),rope(k) bf16 [16,900,96], v^T bf16 [16,96,928]
__global__ __launch_bounds__(256) void k_rope(const float* __restrict__ qkv,
                                              const float* __restrict__ cs,
                                              const float* __restrict__ sn,
                                              ushort* __restrict__ q,
                                              ushort* __restrict__ k,
                                              ushort* __restrict__ vt) {
    int idx = blockIdx.x * 256 + threadIdx.x;
    if (idx >= NT * NH * DHP) return;
    int t = idx / (NH * DHP);
    int rem = idx - t * (NH * DHP);
    int h = rem / DHP, d = rem - h * DHP;
    size_t oi = ((size_t)h * NT + t) * DHP + d;
    if (d < DHD) {
        const float* base = qkv + (size_t)t * 3 * EMB;
        float c = cs[t * DHD + d], s = sn[t * DHD + d];
        int   d2 = (d < DHH) ? d + DHH : d - DHH;
        float sg = (d < DHH) ? -1.f : 1.f;
        int e = h * DHD + d;
        float qv = base[e] * c + sg * base[h * DHD + d2] * s;
        float kv = base[EMB + e] * c + sg * base[EMB + h * DHD + d2] * s;
        q[oi] = f2bf(qv);
        k[oi] = f2bf(kv);
        vt[((size_t)h * DHP + d) * KVP + t] = f2bf(base[2 * EMB + e]);
    } else {
        q[oi] = 0;
        k[oi] = 0;
    }
}

// zero v^T pad columns t in [900,928)
__global__ __launch_bounds__(256) void k_vpad(ushort* __restrict__ vt) {
    int idx = blockIdx.x * 256 + threadIdx.x;
    int tot = NH * DHP * (KVP - NT);
    if (idx >= tot) return;
    int pw = KVP - NT;
    int hd = idx / pw, j = idx - hd * pw;
    vt[(size_t)hd * KVP + NT + j] = 0;
}

// ---------------- softmax: S f32 [16*900][928] -> P bf16 (pad cols zeroed) ----------------
__global__ __launch_bounds__(256) void k_sm(const float* __restrict__ S,
                                            ushort* __restrict__ P) {
    int row = blockIdx.x * 4 + (threadIdx.x >> 6);
    int lane = threadIdx.x & 63;
    const float* sp = S + (size_t)row * KVP;
    ushort* pp = P + (size_t)row * KVP;
    float v[15];
#pragma unroll
    for (int i = 0; i < 15; i++) {
        int kt = lane + i * 64;
        v[i] = (kt < NT) ? sp[kt] : -1e30f;
    }
    float mx = -1e30f;
#pragma unroll
    for (int i = 0; i < 15; i++) mx = fmaxf(mx, v[i]);
    for (int off = 32; off; off >>= 1) mx = fmaxf(mx, __shfl_xor(mx, off, 64));
    float sum = 0.f;
#pragma unroll
    for (int i = 0; i < 15; i++) {
        int kt = lane + i * 64;
        v[i] = (kt < NT) ? __expf(v[i] - mx) : 0.f;
        sum += v[i];
    }
    for (int off = 32; off; off >>= 1) sum += __shfl_xor(sum, off, 64);
    float inv = 1.f / sum;
#pragma unroll
    for (int i = 0; i < 15; i++) {
        int kt = lane + i * 64;
        if (kt < KVP) pp[kt] = f2bf(v[i] * inv);
    }
}

extern "C" void kernel_launch(void* const* d_in, const int* in_sizes, int n_in,
                              void* d_out, int out_size, void* d_ws, size_t ws_size,
                              hipStream_t stream) {
    const float* pix     = (const float*)d_in[0];
    const float* patch_w = (const float*)d_in[1];
    const float* patch_b = (const float*)d_in[2];
    const float* pos_emb = (const float*)d_in[3];
    const float* cosb    = (const float*)d_in[4];
    const float* sinb    = (const float*)d_in[5];
    const float* ln1_w   = (const float*)d_in[6];
    const float* ln1_b   = (const float*)d_in[7];
    const float* qkv_w   = (const float*)d_in[8];
    const float* qkv_b   = (const float*)d_in[9];
    const float* proj_w  = (const float*)d_in[10];
    const float* proj_b  = (const float*)d_in[11];
    const float* ln2_w   = (const float*)d_in[12];
    const float* ln2_b   = (const float*)d_in[13];
    const float* fc1_w   = (const float*)d_in[14];
    const float* fc1_b   = (const float*)d_in[15];
    const float* fc2_w   = (const float*)d_in[16];
    const float* fc2_b   = (const float*)d_in[17];
    const float* dsn_w   = (const float*)d_in[18];
    const float* dsn_b   = (const float*)d_in[19];
    const float* ds1_w   = (const float*)d_in[20];
    const float* ds1_b   = (const float*)d_in[21];
    const float* ds2_w   = (const float*)d_in[22];
    const float* ds2_b   = (const float*)d_in[23];
    const float* mn_w    = (const float*)d_in[24];
    const float* mn_b    = (const float*)d_in[25];
    const float* mf1_w   = (const float*)d_in[26];
    const float* mf1_b   = (const float*)d_in[27];
    const float* mf2_w   = (const float*)d_in[28];
    const float* mf2_b   = (const float*)d_in[29];
    float* out = (float*)d_out;

    // ---- workspace carve (f32 region, then bf16 region) ----
    float* wsf = (float*)d_ws;
    size_t off = 0;
    auto af = [&](size_t n) { float* p = wsf + off; off += (n + 3) & ~(size_t)3; return p; };
    float* h   = af((size_t)NT * EMB);            // residual stream (f32)
    float* qkv = af((size_t)NT * 3 * EMB);        // qkv pre-rope (f32)
    float* S   = af((size_t)NH * NT * KVP);       // attention scores (f32)
    ushort* wsh = (ushort*)(wsf + off);
    size_t hoff = 0;
    auto ah = [&](size_t n) { ushort* p = wsh + hoff; hoff += (n + 7) & ~(size_t)7; return p; };
    ushort* hn  = ah((size_t)NT * EMB);           // LN out (bf16); [900][1152] == [225][4608]
    ushort* qb  = ah((size_t)NH * NT * DHP);
    ushort* kb  = ah((size_t)NH * NT * DHP);
    ushort* vt  = ah((size_t)NH * DHP * KVP);
    ushort* P   = ah((size_t)NH * NT * KVP);      // attention probs (bf16)
    ushort* ob  = ah((size_t)NT * EMB);           // attention out (bf16)
    ushort* t1  = ah((size_t)NT * FFD);           // fc1 out / ds hidden (bf16)
    ushort* xp  = t1;                             // patch matrix reuses t1

    const long QS = (long)NT * DHP;               // q/k head stride
    const long VS = (long)DHP * KVP;              // v^T head stride
    const long SS = (long)NT * KVP;               // scores head stride

    const int MB  = (NT + 63) / 64;   // 15
    const int MBm = (NM + 63) / 64;   // 4

    k_patch<<<dim3((NT * 1536 + 255) / 256), 256, 0, stream>>>(pix, xp);
    k_mm<0, 0, 0><<<dim3(EMB / 64, MB), 256, 0, stream>>>(
        xp, patch_w, patch_b, pos_emb, h, NT, EMB, 1536, EMB, EMB, 0, 0, 0);

    for (int l = 0; l < NL; ++l) {
        k_ln<<<NT, 256, 0, stream>>>(h, ln1_w + l * EMB, ln1_b + l * EMB, hn, EMB);
        k_mm<0, 0, 0><<<dim3(3 * EMB / 64, MB), 256, 0, stream>>>(
            hn, qkv_w + (size_t)l * 3 * EMB * EMB, qkv_b + l * 3 * EMB, nullptr, qkv,
            NT, 3 * EMB, EMB, 3 * EMB, 3 * EMB, 0, 0, 0);
        k_rope<<<dim3((NT * NH * DHP + 255) / 256), 256, 0, stream>>>(
            qkv, cosb, sinb, qb, kb, vt);
        k_vpad<<<dim3((NH * DHP * (KVP - NT) + 255) / 256), 256, 0, stream>>>(vt);
        // S = Q @ K^T  (per head)
        k_mm<0, 1, 0><<<dim3(MB, MB, NH), 256, 0, stream>>>(
            qb, kb, nullptr, nullptr, S, NT, NT, DHP, KVP, NT, QS, QS, SS);
        k_sm<<<dim3(NH * NT / 4), 256, 0, stream>>>(S, P);
        // O = P @ V  (per head) -> ob bf16 [900][1152]
        k_mm<0, 1, 1><<<dim3(2, MB, NH), 256, 0, stream>>>(
            P, vt, nullptr, nullptr, ob, NT, DHD, KVP, EMB, DHD, SS, VS, DHD);
        k_mm<0, 0, 0><<<dim3(EMB / 64, MB), 256, 0, stream>>>(
            ob, proj_w + (size_t)l * EMB * EMB, proj_b + l * EMB, h, h,
            NT, EMB, EMB, EMB, EMB, 0, 0, 0);
        k_ln<<<NT, 256, 0, stream>>>(h, ln2_w + l * EMB, ln2_b + l * EMB, hn, EMB);
        k_mm<1, 0, 1><<<dim3(FFD / 64, MB), 256, 0, stream>>>(
            hn, fc1_w + (size_t)l * FFD * EMB, fc1_b + l * FFD, nullptr, t1,
            NT, FFD, EMB, FFD, FFD, 0, 0, 0);
        k_mm<0, 0, 0><<<dim3(EMB / 64, MB), 256, 0, stream>>>(
            t1, fc2_w + (size_t)l * EMB * FFD, fc2_b + l * EMB, h, h,
            NT, EMB, FFD, EMB, EMB, 0, 0, 0);
        if (l == 2 || l == 5) {
            int d = (l == 2) ? 0 : 1;
            k_ln<<<NM, 256, 0, stream>>>(h, dsn_w + d * MHD, dsn_b + d * MHD, hn, MHD);
            k_mm<1, 0, 1><<<dim3(MHD / 64, MBm), 256, 0, stream>>>(
                hn, ds1_w + (size_t)d * MHD * MHD, ds1_b + d * MHD, nullptr, t1,
                NM, MHD, MHD, MHD, MHD, 0, 0, 0);
            k_mm<0, 0, 0><<<dim3(OUTD / 64, MBm), 256, 0, stream>>>(
                t1, ds2_w + (size_t)d * OUTD * MHD, ds2_b + d * OUTD, nullptr,
                out + (size_t)d * NM * OUTD, NM, OUTD, MHD, OUTD, OUTD, 0, 0, 0);
        }
    }
    // merger LN is over EMB=1152 per token (900 rows), THEN reshaped to [225][4608]
    k_ln<<<NT, 256, 0, stream>>>(h, mn_w, mn_b, hn, EMB);
    k_mm<1, 0, 1><<<dim3(MHD / 64, MBm), 256, 0, stream>>>(
        hn, mf1_w, mf1_b, nullptr, t1, NM, MHD, MHD, MHD, MHD, 0, 0, 0);
    k_mm<0, 0, 0><<<dim3(OUTD / 64, MBm), 256, 0, stream>>>(
        t1, mf2_w, mf2_b, nullptr, out + (size_t)2 * NM * OUTD,
        NM, OUTD, MHD, OUTD, OUTD, 0, 0, 0);
}

// Round 4
// 1736.798 us; speedup vs baseline: 5.3977x; 1.5497x over previous
//
#include <hip/hip_runtime.h>
#include <hip/hip_bf16.h>
#include <cstdint>

#define NT   900
#define EMB  1152
#define NH   16
#define DHD  72
#define DHH  36
#define DHP  96      // padded head dim (3*32)
#define KVP  928     // padded kv length (29*32)
#define NL   6
#define FFD  4608
#define MHD  4608
#define OUTD 2048
#define NM   225

typedef __attribute__((ext_vector_type(8))) short short8;
typedef __attribute__((ext_vector_type(4))) float f32x4;

__device__ __forceinline__ ushort f2bf(float f) {
    uint32_t u = __float_as_uint(f);
    uint32_t r = u + 0x7FFF + ((u >> 16) & 1);
    return (ushort)(r >> 16);
}
__device__ __forceinline__ float gelu_f(float x) {
    return 0.5f * x * (1.0f + tanhf(0.7978845608f * (x + 0.044715f * x * x * x)));
}

// ---------------- patch extraction: pixels -> bf16 [900, 1536] ----------------
__global__ __launch_bounds__(256) void k_patch(const float* __restrict__ pix,
                                               ushort* __restrict__ xp) {
    int idx = blockIdx.x * 256 + threadIdx.x;
    if (idx >= NT * 1536) return;
    int t = idx / 1536, f = idx - t * 1536;
    int mw = t & 1, mh = (t >> 1) & 1;
    int tq = t >> 2;
    int jj = tq % 15, ii = tq / 15;
    int pw = f & 15, ph = (f >> 4) & 15, c = f >> 9;
    int Hi = (ii * 2 + mh) * 16 + ph;
    int Wi = (jj * 2 + mw) * 16 + pw;
    float p = pix[((size_t)c * 480 + Hi) * 480 + Wi];
    xp[idx] = f2bf((p - 127.5f) * (1.0f / 127.5f));
}

// ---------------- layernorm f32 in -> bf16 out, one block per row ----------------
__global__ __launch_bounds__(256) void k_ln(const float* __restrict__ x,
                                            const float* __restrict__ w,
                                            const float* __restrict__ b,
                                            ushort* __restrict__ y, int C) {
    int row = blockIdx.x;
    int tid = threadIdx.x;
    const float* xr = x + (size_t)row * C;
    float s = 0.f, ss = 0.f;
    for (int c = tid; c < C; c += 256) { float v = xr[c]; s += v; ss += v * v; }
    for (int off = 32; off; off >>= 1) {
        s  += __shfl_down(s,  off, 64);
        ss += __shfl_down(ss, off, 64);
    }
    __shared__ float rs[4], rss[4];
    int wid = tid >> 6, lane = tid & 63;
    if (lane == 0) { rs[wid] = s; rss[wid] = ss; }
    __syncthreads();
    float S  = rs[0] + rs[1] + rs[2] + rs[3];
    float SS = rss[0] + rss[1] + rss[2] + rss[3];
    float mu  = S / C;
    float var = SS / C - mu * mu;
    float inv = rsqrtf(var + 1e-6f);
    ushort* yr = y + (size_t)row * C;
    for (int c = tid; c < C; c += 256) yr[c] = f2bf((xr[c] - mu) * inv * w[c] + b[c]);
}

// ---------------- dense MFMA GEMM, BK=64, reg-prefetch, optional split-K ----
// C[M,N] = act(A[M,K](bf16) @ W[N,K]^T(f32) + bias) + res     (N % 64 == 0)
// grid (Mt, Nt, S). SPLIT=1: raw partials to part[z][M][N]; epilogue in k_fix.
template <int ACT, int OBF16, int SPLIT>
__global__ __launch_bounds__(256) void k_gsk(const ushort* __restrict__ A,
                                             const float* __restrict__ W,
                                             const float* __restrict__ bias,
                                             const float* __restrict__ res,
                                             void* __restrict__ Cp,
                                             float* __restrict__ part,
                                             int M, int N, int K, int S) {
    __shared__ __align__(16) ushort As[64 * 72];
    __shared__ __align__(16) ushort Bs[64 * 72];
    int tid = threadIdx.x;
    int row0 = blockIdx.x * 64, col0 = blockIdx.y * 64;
    int z = blockIdx.z;
    int Kc = K / S;              // multiple of 64
    int kbeg = z * Kc;
    int steps = Kc >> 6;

    int srow = tid >> 2;
    int scol = (tid & 3) << 4;   // 16-elem units
    int ar = row0 + srow; if (ar > M - 1) ar = M - 1;
    int wr = col0 + srow;
    const ushort* aptr = A + (size_t)ar * K + kbeg + scol;
    const float*  wptr = W + (size_t)wr * K + kbeg + scol;
    ushort* asd = &As[srow * 72 + scol];
    ushort* bsd = &Bs[srow * 72 + scol];

    uint4 ra0, ra1;
    float4 rw0, rw1, rw2, rw3;
#define LOADCHUNK(s)                                                     \
    { const ushort* p = aptr + ((s) << 6);                               \
      ra0 = *(const uint4*)p; ra1 = *(const uint4*)(p + 8);              \
      const float* q = wptr + ((s) << 6);                                \
      rw0 = *(const float4*)q;       rw1 = *(const float4*)(q + 4);      \
      rw2 = *(const float4*)(q + 8); rw3 = *(const float4*)(q + 12); }

    int lane = tid & 63, wid = tid >> 6;
    int wrr = (wid >> 1) * 32, wcc = (wid & 1) * 32;
    int fr = lane & 15, kg8 = (lane >> 4) << 3;

    f32x4 acc[2][2] = {};
    LOADCHUNK(0);
    for (int s = 0; s < steps; ++s) {
        __syncthreads();
        *(uint4*)asd = ra0; *(uint4*)(asd + 8) = ra1;
        ushort wa[8] = { f2bf(rw0.x), f2bf(rw0.y), f2bf(rw0.z), f2bf(rw0.w),
                         f2bf(rw1.x), f2bf(rw1.y), f2bf(rw1.z), f2bf(rw1.w) };
        ushort wb[8] = { f2bf(rw2.x), f2bf(rw2.y), f2bf(rw2.z), f2bf(rw2.w),
                         f2bf(rw3.x), f2bf(rw3.y), f2bf(rw3.z), f2bf(rw3.w) };
        *(uint4*)bsd = *(const uint4*)wa; *(uint4*)(bsd + 8) = *(const uint4*)wb;
        if (s + 1 < steps) LOADCHUNK(s + 1);
        __syncthreads();
#pragma unroll
        for (int j = 0; j < 2; ++j) {
            int ko = j * 32 + kg8;
            short8 a0 = *(const short8*)&As[(wrr + fr) * 72 + ko];
            short8 a1 = *(const short8*)&As[(wrr + 16 + fr) * 72 + ko];
            short8 b0 = *(const short8*)&Bs[(wcc + fr) * 72 + ko];
            short8 b1 = *(const short8*)&Bs[(wcc + 16 + fr) * 72 + ko];
            acc[0][0] = __builtin_amdgcn_mfma_f32_16x16x32_bf16(a0, b0, acc[0][0], 0, 0, 0);
            acc[0][1] = __builtin_amdgcn_mfma_f32_16x16x32_bf16(a0, b1, acc[0][1], 0, 0, 0);
            acc[1][0] = __builtin_amdgcn_mfma_f32_16x16x32_bf16(a1, b0, acc[1][0], 0, 0, 0);
            acc[1][1] = __builtin_amdgcn_mfma_f32_16x16x32_bf16(a1, b1, acc[1][1], 0, 0, 0);
        }
    }
#undef LOADCHUNK

#pragma unroll
    for (int fi = 0; fi < 2; fi++)
#pragma unroll
        for (int fj = 0; fj < 2; fj++)
#pragma unroll
            for (int r = 0; r < 4; r++) {
                int row = row0 + wrr + fi * 16 + (lane >> 4) * 4 + r;
                int col = col0 + wcc + fj * 16 + fr;
                if (row < M) {
                    if (SPLIT) {
                        part[((size_t)z * M + row) * N + col] = acc[fi][fj][r];
                    } else {
                        float v = acc[fi][fj][r] + bias[col];
                        if (res) v += res[(size_t)row * N + col];
                        if (ACT == 1) v = gelu_f(v);
                        if (OBF16) ((ushort*)Cp)[(size_t)row * N + col] = f2bf(v);
                        else       ((float*)Cp)[(size_t)row * N + col] = v;
                    }
                }
            }
}

// ---------------- split-K fixup: out = act(sum_s part + bias + res) ----------------
template <int ACT, int OBF16>
__global__ __launch_bounds__(256) void k_fix(const float* __restrict__ part,
                                             const float* __restrict__ bias,
                                             const float* __restrict__ res,
                                             void* __restrict__ Cp,
                                             int M, int N, int S) {
    size_t idx = (size_t)blockIdx.x * 256 + threadIdx.x;
    size_t total = (size_t)M * N / 4;
    if (idx >= total) return;
    size_t e = idx * 4;
    int row = (int)(e / N), col = (int)(e - (size_t)row * N);
    float4 v = *(const float4*)(part + e);
    for (int s = 1; s < S; ++s) {
        const float4 p = *(const float4*)(part + (size_t)s * M * N + e);
        v.x += p.x; v.y += p.y; v.z += p.z; v.w += p.w;
    }
    const float4 bi = *(const float4*)(bias + col);
    v.x += bi.x; v.y += bi.y; v.z += bi.z; v.w += bi.w;
    if (res) {
        const float4 rr = *(const float4*)(res + e);
        v.x += rr.x; v.y += rr.y; v.z += rr.z; v.w += rr.w;
    }
    if (ACT == 1) { v.x = gelu_f(v.x); v.y = gelu_f(v.y); v.z = gelu_f(v.z); v.w = gelu_f(v.w); }
    if (OBF16) {
        ushort o[4] = { f2bf(v.x), f2bf(v.y), f2bf(v.z), f2bf(v.w) };
        *(uint2*)((ushort*)Cp + e) = *(const uint2*)o;
    } else {
        *(float4*)((float*)Cp + e) = v;
    }
}

// ---------------- attention GEMM (bf16 A & W, batched over heads), BK=32 ----
template <int OBF16>
__global__ __launch_bounds__(256) void k_mm(const ushort* __restrict__ A,
                                            const ushort* __restrict__ Wb,
                                            void* __restrict__ Cp,
                                            int M, int N, int K, int ldc, int Nw,
                                            long as_, long ws_, long cs_) {
    __shared__ __align__(16) ushort As[64 * 40];
    __shared__ __align__(16) ushort Bs[64 * 40];
    int z = blockIdx.z;
    A  += (size_t)z * as_;
    Wb += (size_t)z * ws_;
    float*  Cf = (float*)Cp + (size_t)z * cs_;
    ushort* Cb = (ushort*)Cp + (size_t)z * cs_;

    int tid = threadIdx.x;
    int row0 = blockIdx.y * 64, col0 = blockIdx.x * 64;

    int sm = tid >> 2, sp = tid & 3;
    int ar = row0 + sm; if (ar > M - 1) ar = M - 1;
    int wr = col0 + sm; if (wr > N - 1) wr = N - 1;
    const ushort* aptr = A + (size_t)ar * K;

    int lane = tid & 63, wid = tid >> 6;
    int wrr = (wid >> 1) * 32, wcc = (wid & 1) * 32;
    int fr = lane & 15, kg = lane >> 4;

    f32x4 acc[2][2] = {};

    for (int k0 = 0; k0 < K; k0 += 32) {
        *(uint4*)&As[sm * 40 + sp * 8] = *(const uint4*)(aptr + k0 + sp * 8);
        *(uint4*)&Bs[sm * 40 + sp * 8] = *(const uint4*)(Wb + (size_t)wr * K + k0 + sp * 8);
        __syncthreads();
        short8 a0 = *(const short8*)&As[(wrr + fr) * 40 + kg * 8];
        short8 a1 = *(const short8*)&As[(wrr + 16 + fr) * 40 + kg * 8];
        short8 b0 = *(const short8*)&Bs[(wcc + fr) * 40 + kg * 8];
        short8 b1 = *(const short8*)&Bs[(wcc + 16 + fr) * 40 + kg * 8];
        acc[0][0] = __builtin_amdgcn_mfma_f32_16x16x32_bf16(a0, b0, acc[0][0], 0, 0, 0);
        acc[0][1] = __builtin_amdgcn_mfma_f32_16x16x32_bf16(a0, b1, acc[0][1], 0, 0, 0);
        acc[1][0] = __builtin_amdgcn_mfma_f32_16x16x32_bf16(a1, b0, acc[1][0], 0, 0, 0);
        acc[1][1] = __builtin_amdgcn_mfma_f32_16x16x32_bf16(a1, b1, acc[1][1], 0, 0, 0);
        __syncthreads();
    }

#pragma unroll
    for (int fi = 0; fi < 2; fi++)
#pragma unroll
        for (int fj = 0; fj < 2; fj++)
#pragma unroll
            for (int r = 0; r < 4; r++) {
                int row = row0 + wrr + fi * 16 + (lane >> 4) * 4 + r;
                int col = col0 + wcc + fj * 16 + (lane & 15);
                if (row < M && col < Nw) {
                    float v = acc[fi][fj][r];
                    if (OBF16) Cb[(size_t)row * ldc + col] = f2bf(v);
                    else       Cf[(size_t)row * ldc + col] = v;
                }
            }
}

// ---------------- qkv f32 [900,3456] -> rope(q),rope(k) bf16 [16,900,96], v^T bf16 [16,96,928]
__global__ __launch_bounds__(256) void k_rope(const float* __restrict__ qkv,
                                              const float* __restrict__ cs,
                                              const float* __restrict__ sn,
                                              ushort* __restrict__ q,
                                              ushort* __restrict__ k,
                                              ushort* __restrict__ vt) {
    int idx = blockIdx.x * 256 + threadIdx.x;
    if (idx >= NT * NH * DHP) return;
    int t = idx / (NH * DHP);
    int rem = idx - t * (NH * DHP);
    int h = rem / DHP, d = rem - h * DHP;
    size_t oi = ((size_t)h * NT + t) * DHP + d;
    if (d < DHD) {
        const float* base = qkv + (size_t)t * 3 * EMB;
        float c = cs[t * DHD + d], s = sn[t * DHD + d];
        int   d2 = (d < DHH) ? d + DHH : d - DHH;
        float sg = (d < DHH) ? -1.f : 1.f;
        int e = h * DHD + d;
        float qv = base[e] * c + sg * base[h * DHD + d2] * s;
        float kv = base[EMB + e] * c + sg * base[EMB + h * DHD + d2] * s;
        q[oi] = f2bf(qv);
        k[oi] = f2bf(kv);
        vt[((size_t)h * DHP + d) * KVP + t] = f2bf(base[2 * EMB + e]);
    } else {
        q[oi] = 0;
        k[oi] = 0;
    }
}

// zero v^T pad columns t in [900,928)
__global__ __launch_bounds__(256) void k_vpad(ushort* __restrict__ vt) {
    int idx = blockIdx.x * 256 + threadIdx.x;
    int tot = NH * DHP * (KVP - NT);
    if (idx >= tot) return;
    int pw = KVP - NT;
    int hd = idx / pw, j = idx - hd * pw;
    vt[(size_t)hd * KVP + NT + j] = 0;
}

// ---------------- softmax: S f32 [16*900][928] -> P bf16 (pad cols zeroed) ----------------
__global__ __launch_bounds__(256) void k_sm(const float* __restrict__ S,
                                            ushort* __restrict__ P) {
    int row = blockIdx.x * 4 + (threadIdx.x >> 6);
    int lane = threadIdx.x & 63;
    const float* sp = S + (size_t)row * KVP;
    ushort* pp = P + (size_t)row * KVP;
    float v[15];
#pragma unroll
    for (int i = 0; i < 15; i++) {
        int kt = lane + i * 64;
        v[i] = (kt < NT) ? sp[kt] : -1e30f;
    }
    float mx = -1e30f;
#pragma unroll
    for (int i = 0; i < 15; i++) mx = fmaxf(mx, v[i]);
    for (int off = 32; off; off >>= 1) mx = fmaxf(mx, __shfl_xor(mx, off, 64));
    float sum = 0.f;
#pragma unroll
    for (int i = 0; i < 15; i++) {
        int kt = lane + i * 64;
        v[i] = (kt < NT) ? __expf(v[i] - mx) : 0.f;
        sum += v[i];
    }
    for (int off = 32; off; off >>= 1) sum += __shfl_xor(sum, off, 64);
    float inv = 1.f / sum;
#pragma unroll
    for (int i = 0; i < 15; i++) {
        int kt = lane + i * 64;
        if (kt < KVP) pp[kt] = f2bf(v[i] * inv);
    }
}

extern "C" void kernel_launch(void* const* d_in, const int* in_sizes, int n_in,
                              void* d_out, int out_size, void* d_ws, size_t ws_size,
                              hipStream_t stream) {
    const float* pix     = (const float*)d_in[0];
    const float* patch_w = (const float*)d_in[1];
    const float* patch_b = (const float*)d_in[2];
    const float* pos_emb = (const float*)d_in[3];
    const float* cosb    = (const float*)d_in[4];
    const float* sinb    = (const float*)d_in[5];
    const float* ln1_w   = (const float*)d_in[6];
    const float* ln1_b   = (const float*)d_in[7];
    const float* qkv_w   = (const float*)d_in[8];
    const float* qkv_b   = (const float*)d_in[9];
    const float* proj_w  = (const float*)d_in[10];
    const float* proj_b  = (const float*)d_in[11];
    const float* ln2_w   = (const float*)d_in[12];
    const float* ln2_b   = (const float*)d_in[13];
    const float* fc1_w   = (const float*)d_in[14];
    const float* fc1_b   = (const float*)d_in[15];
    const float* fc2_w   = (const float*)d_in[16];
    const float* fc2_b   = (const float*)d_in[17];
    const float* dsn_w   = (const float*)d_in[18];
    const float* dsn_b   = (const float*)d_in[19];
    const float* ds1_w   = (const float*)d_in[20];
    const float* ds1_b   = (const float*)d_in[21];
    const float* ds2_w   = (const float*)d_in[22];
    const float* ds2_b   = (const float*)d_in[23];
    const float* mn_w    = (const float*)d_in[24];
    const float* mn_b    = (const float*)d_in[25];
    const float* mf1_w   = (const float*)d_in[26];
    const float* mf1_b   = (const float*)d_in[27];
    const float* mf2_w   = (const float*)d_in[28];
    const float* mf2_b   = (const float*)d_in[29];
    float* out = (float*)d_out;

    // ---- workspace carve (f32 region, then bf16 region) ----
    float* wsf = (float*)d_ws;
    size_t off = 0;
    auto af = [&](size_t n) { float* p = wsf + off; off += (n + 3) & ~(size_t)3; return p; };
    float* h   = af((size_t)NT * EMB);            // residual stream (f32)
    float* qkv = af((size_t)NT * 3 * EMB);        // qkv pre-rope (f32)
    float* S   = af((size_t)NH * NT * KVP);       // attention scores; aliased as split-K partials
    float* part = S;
    ushort* wsh = (ushort*)(wsf + off);
    size_t hoff = 0;
    auto ah = [&](size_t n) { ushort* p = wsh + hoff; hoff += (n + 7) & ~(size_t)7; return p; };
    ushort* hn  = ah((size_t)NT * EMB);           // LN out (bf16); [900][1152] == [225][4608]
    ushort* qb  = ah((size_t)NH * NT * DHP);
    ushort* kb  = ah((size_t)NH * NT * DHP);
    ushort* vt  = ah((size_t)NH * DHP * KVP);
    ushort* P   = ah((size_t)NH * NT * KVP);      // attention probs (bf16)
    ushort* ob  = ah((size_t)NT * EMB);           // attention out (bf16)
    ushort* t1  = ah((size_t)NT * FFD);           // fc1 out / ds hidden (bf16)
    ushort* xp  = t1;                             // patch matrix reuses t1

    const long QS = (long)NT * DHP;
    const long VS = (long)DHP * KVP;
    const long SS = (long)NT * KVP;

    const int MB  = (NT + 63) / 64;   // 15
    const int MBm = (NM + 63) / 64;   // 4
    auto fixg = [](int M, int N) { return dim3(((size_t)M * N / 4 + 255) / 256); };

    k_patch<<<dim3((NT * 1536 + 255) / 256), 256, 0, stream>>>(pix, xp);
    // patch embed: M=900 N=1152 K=1536, S=2
    k_gsk<0, 0, 1><<<dim3(MB, EMB / 64, 2), 256, 0, stream>>>(
        xp, patch_w, nullptr, nullptr, nullptr, part, NT, EMB, 1536, 2);
    k_fix<0, 0><<<fixg(NT, EMB), 256, 0, stream>>>(part, patch_b, pos_emb, h, NT, EMB, 2);

    for (int l = 0; l < NL; ++l) {
        k_ln<<<NT, 256, 0, stream>>>(h, ln1_w + l * EMB, ln1_b + l * EMB, hn, EMB);
        // qkv: M=900 N=3456 K=1152, S=1 (810 blocks)
        k_gsk<0, 0, 0><<<dim3(MB, 3 * EMB / 64, 1), 256, 0, stream>>>(
            hn, qkv_w + (size_t)l * 3 * EMB * EMB, qkv_b + l * 3 * EMB, nullptr, qkv,
            nullptr, NT, 3 * EMB, EMB, 1);
        k_rope<<<dim3((NT * NH * DHP + 255) / 256), 256, 0, stream>>>(
            qkv, cosb, sinb, qb, kb, vt);
        k_vpad<<<dim3((NH * DHP * (KVP - NT) + 255) / 256), 256, 0, stream>>>(vt);
        // S = Q @ K^T (per head)
        k_mm<0><<<dim3(MB, MB, NH), 256, 0, stream>>>(
            qb, kb, S, NT, NT, DHP, KVP, NT, QS, QS, SS);
        k_sm<<<dim3(NH * NT / 4), 256, 0, stream>>>(S, P);
        // O = P @ V (per head) -> ob bf16 [900][1152]
        k_mm<1><<<dim3(2, MB, NH), 256, 0, stream>>>(
            P, vt, ob, NT, DHD, KVP, EMB, DHD, SS, VS, DHD);
        // proj: M=900 N=1152 K=1152, S=3
        k_gsk<0, 0, 1><<<dim3(MB, EMB / 64, 3), 256, 0, stream>>>(
            ob, proj_w + (size_t)l * EMB * EMB, nullptr, nullptr, nullptr, part,
            NT, EMB, EMB, 3);
        k_fix<0, 0><<<fixg(NT, EMB), 256, 0, stream>>>(part, proj_b + l * EMB, h, h,
                                                       NT, EMB, 3);
        k_ln<<<NT, 256, 0, stream>>>(h, ln2_w + l * EMB, ln2_b + l * EMB, hn, EMB);
        // fc1: M=900 N=4608 K=1152, S=1 (1080 blocks)
        k_gsk<1, 1, 0><<<dim3(MB, FFD / 64, 1), 256, 0, stream>>>(
            hn, fc1_w + (size_t)l * FFD * EMB, fc1_b + l * FFD, nullptr, t1,
            nullptr, NT, FFD, EMB, 1);
        // fc2: M=900 N=1152 K=4608, S=4
        k_gsk<0, 0, 1><<<dim3(MB, EMB / 64, 4), 256, 0, stream>>>(
            t1, fc2_w + (size_t)l * EMB * FFD, nullptr, nullptr, nullptr, part,
            NT, EMB, FFD, 4);
        k_fix<0, 0><<<fixg(NT, EMB), 256, 0, stream>>>(part, fc2_b + l * EMB, h, h,
                                                       NT, EMB, 4);
        if (l == 2 || l == 5) {
            int d = (l == 2) ? 0 : 1;
            k_ln<<<NM, 256, 0, stream>>>(h, dsn_w + d * MHD, dsn_b + d * MHD, hn, MHD);
            // ds1: M=225 N=4608 K=4608, S=4
            k_gsk<0, 0, 1><<<dim3(MBm, MHD / 64, 4), 256, 0, stream>>>(
                hn, ds1_w + (size_t)d * MHD * MHD, nullptr, nullptr, nullptr, part,
                NM, MHD, MHD, 4);
            k_fix<1, 1><<<fixg(NM, MHD), 256, 0, stream>>>(part, ds1_b + d * MHD,
                                                           nullptr, t1, NM, MHD, 4);
            // ds2: M=225 N=2048 K=4608, S=4
            k_gsk<0, 0, 1><<<dim3(MBm, OUTD / 64, 4), 256, 0, stream>>>(
                t1, ds2_w + (size_t)d * OUTD * MHD, nullptr, nullptr, nullptr, part,
                NM, OUTD, MHD, 4);
            k_fix<0, 0><<<fixg(NM, OUTD), 256, 0, stream>>>(
                part, ds2_b + d * OUTD, nullptr, out + (size_t)d * NM * OUTD,
                NM, OUTD, 4);
        }
    }
    // merger LN is over EMB=1152 per token (900 rows), THEN reshaped to [225][4608]
    k_ln<<<NT, 256, 0, stream>>>(h, mn_w, mn_b, hn, EMB);
    k_gsk<0, 0, 1><<<dim3(MBm, MHD / 64, 4), 256, 0, stream>>>(
        hn, mf1_w, nullptr, nullptr, nullptr, part, NM, MHD, MHD, 4);
    k_fix<1, 1><<<fixg(NM, MHD), 256, 0, stream>>>(part, mf1_b, nullptr, t1, NM, MHD, 4);
    k_gsk<0, 0, 1><<<dim3(MBm, OUTD / 64, 4), 256, 0, stream>>>(
        t1, mf2_w, nullptr, nullptr, nullptr, part, NM, OUTD, MHD, 4);
    k_fix<0, 0><<<fixg(NM, OUTD), 256, 0, stream>>>(
        part, mf2_b, nullptr, out + (size_t)2 * NM * OUTD, NM, OUTD, 4);
}